// Round 2
// baseline (620.979 us; speedup 1.0000x reference)
//
#include <hip/hip_runtime.h>

#define IN_FEATS 256
#define OUT_FEATS 32
#define NUM_HEADS 4
#define NHF 128   // NUM_HEADS*OUT_FEATS

#define BM 64
#define BK 32

// v[k*4+h] = sum_f W[k*128 + h*32 + f] * attn_r[h*32 + f]
__global__ void compute_v(const float* __restrict__ W, const float* __restrict__ attn_r,
                          float* __restrict__ v) {
    for (int p = threadIdx.x; p < IN_FEATS * NUM_HEADS; p += blockDim.x) {
        int k = p >> 2, h = p & 3;
        const float* wr = W + (size_t)k * NHF + h * OUT_FEATS;
        const float* ar = attn_r + h * OUT_FEATS;
        float s = 0.f;
        #pragma unroll
        for (int f = 0; f < OUT_FEATS; ++f) s += wr[f] * ar[f];
        v[p] = s;
    }
}

// ft = A @ W : [M,256] x [256,128] -> [M,128], fp32 VALU tiled
__global__ __launch_bounds__(256) void gemm_ft(const float* __restrict__ A,
                                               const float* __restrict__ W,
                                               float* __restrict__ ft, int M) {
    __shared__ float As[BM][BK + 1];
    __shared__ float Bs[BK][NHF];
    const int tid = threadIdx.x;
    const int ty = tid >> 5;   // 0..7 : rows ty*8 .. ty*8+7
    const int tx = tid & 31;   // 0..31: cols tx + 32*j
    const int bm = blockIdx.x * BM;
    float acc[8][4];
    #pragma unroll
    for (int i = 0; i < 8; ++i)
        #pragma unroll
        for (int j = 0; j < 4; ++j) acc[i][j] = 0.f;

    for (int k0 = 0; k0 < IN_FEATS; k0 += BK) {
        // A tile: 64x32 floats = 512 float4, 2 per thread
        for (int t = tid; t < 512; t += 256) {
            int r = t >> 3;
            int c = (t & 7) << 2;
            float4 vv = make_float4(0.f, 0.f, 0.f, 0.f);
            int row = bm + r;
            if (row < M) vv = *(const float4*)(A + (size_t)row * IN_FEATS + k0 + c);
            As[r][c] = vv.x; As[r][c + 1] = vv.y; As[r][c + 2] = vv.z; As[r][c + 3] = vv.w;
        }
        // B tile: 32x128 floats = 1024 float4, 4 per thread
        for (int t = tid; t < 1024; t += 256) {
            int r = t >> 5;
            int c = (t & 31) << 2;
            *(float4*)(&Bs[r][c]) = *(const float4*)(W + (size_t)(k0 + r) * NHF + c);
        }
        __syncthreads();
        #pragma unroll
        for (int k = 0; k < BK; ++k) {
            float a[8], b[4];
            #pragma unroll
            for (int i = 0; i < 8; ++i) a[i] = As[ty * 8 + i][k];
            #pragma unroll
            for (int j = 0; j < 4; ++j) b[j] = Bs[k][tx + 32 * j];
            #pragma unroll
            for (int i = 0; i < 8; ++i)
                #pragma unroll
                for (int j = 0; j < 4; ++j) acc[i][j] += a[i] * b[j];
        }
        __syncthreads();
    }
    #pragma unroll
    for (int i = 0; i < 8; ++i) {
        int row = bm + ty * 8 + i;
        if (row < M) {
            float* o = ft + (size_t)row * NHF;
            #pragma unroll
            for (int j = 0; j < 4; ++j) o[tx + 32 * j] = acc[i][j];
        }
    }
}

// el[n*4+h] = sum_f ft[n*128 + h*32 + f] * attn_l[h*32 + f]
__global__ void compute_el(const float* __restrict__ ft, const float* __restrict__ attn_l,
                           float* __restrict__ el, int M) {
    int t = blockIdx.x * blockDim.x + threadIdx.x;
    if (t >= M * NUM_HEADS) return;
    int n = t >> 2, h = t & 3;
    const float4* row = (const float4*)(ft + (size_t)n * NHF + h * OUT_FEATS);
    const float4* al  = (const float4*)(attn_l + h * OUT_FEATS);
    float s = 0.f;
    #pragma unroll
    for (int f = 0; f < 8; ++f) {
        float4 x = row[f], y = al[f];
        s += x.x * y.x + x.y * y.y + x.z * y.z + x.w * y.w;
    }
    el[t] = s;
}

// er[n*4+h] = sum_k h_dst[n*256+k] * v[k*4+h]   (one wave per row)
__global__ __launch_bounds__(256) void compute_er(const float* __restrict__ hdst,
                                                  const float* __restrict__ v,
                                                  float* __restrict__ er, int M) {
    int wid  = (blockIdx.x * blockDim.x + threadIdx.x) >> 6;
    int lane = threadIdx.x & 63;
    if (wid >= M) return;
    const float4 x = *(const float4*)(hdst + (size_t)wid * IN_FEATS + lane * 4);
    const float4* vp = (const float4*)(v + (size_t)lane * 16);
    float4 v0 = vp[0], v1 = vp[1], v2 = vp[2], v3 = vp[3];
    float a0 = x.x * v0.x + x.y * v1.x + x.z * v2.x + x.w * v3.x;
    float a1 = x.x * v0.y + x.y * v1.y + x.z * v2.y + x.w * v3.y;
    float a2 = x.x * v0.z + x.y * v1.z + x.z * v2.z + x.w * v3.z;
    float a3 = x.x * v0.w + x.y * v1.w + x.z * v2.w + x.w * v3.w;
    #pragma unroll
    for (int m = 32; m >= 1; m >>= 1) {
        a0 += __shfl_xor(a0, m, 64);
        a1 += __shfl_xor(a1, m, 64);
        a2 += __shfl_xor(a2, m, 64);
        a3 += __shfl_xor(a3, m, 64);
    }
    if (lane == 0) *(float4*)(er + (size_t)wid * 4) = make_float4(a0, a1, a2, a3);
}

// per (e,h): w = exp(leaky_relu(el[src]+er[dst])); ssum[dst,h] += w
__global__ void edge_exp(const int* __restrict__ src, const int* __restrict__ dst,
                         const float* __restrict__ el, const float* __restrict__ er,
                         float* __restrict__ w, float* __restrict__ ssum, int E) {
    int t = blockIdx.x * blockDim.x + threadIdx.x;
    if (t >= E * NUM_HEADS) return;
    int e = t >> 2, h = t & 3;
    int s = src[e], d = dst[e];
    float x = el[s * 4 + h] + er[d * 4 + h];
    x = x > 0.f ? x : 0.2f * x;
    float ex = __expf(x);
    w[t] = ex;
    atomicAdd(ssum + d * 4 + h, ex);
}

__global__ void edge_norm(const int* __restrict__ dst, const float* __restrict__ ssum,
                          float* __restrict__ w, int E) {
    int t = blockIdx.x * blockDim.x + threadIdx.x;
    if (t >= E * NUM_HEADS) return;
    int e = t >> 2, h = t & 3;
    w[t] = w[t] / ssum[dst[e] * 4 + h];
}

// one wave per edge: out[dst, :] += ft[src, :] * a[e, h(:)]
__global__ __launch_bounds__(256) void agg(const int* __restrict__ src, const int* __restrict__ dst,
                                           const float* __restrict__ ft, const float* __restrict__ a,
                                           float* __restrict__ out, int E) {
    int wid  = (blockIdx.x * blockDim.x + threadIdx.x) >> 6;
    int lane = threadIdx.x & 63;
    if (wid >= E) return;
    int s = src[wid], d = dst[wid];
    const float* fs = ft + (size_t)s * NHF;
    float* o = out + (size_t)d * NHF;
    float a0 = a[(size_t)wid * 4 + (lane >> 5)];
    float a1 = a[(size_t)wid * 4 + 2 + (lane >> 5)];
    atomicAdd(o + lane,      fs[lane]      * a0);
    atomicAdd(o + 64 + lane, fs[64 + lane] * a1);
}

extern "C" void kernel_launch(void* const* d_in, const int* in_sizes, int n_in,
                              void* d_out, int out_size, void* d_ws, size_t ws_size,
                              hipStream_t stream) {
    const float* h_src  = (const float*)d_in[0];
    const float* h_dst  = (const float*)d_in[1];
    const float* W      = (const float*)d_in[2];
    const float* attn_l = (const float*)d_in[3];
    const float* attn_r = (const float*)d_in[4];
    const int* src_idx  = (const int*)d_in[5];
    const int* dst_idx  = (const int*)d_in[6];

    const int n_src = in_sizes[0] / IN_FEATS;   // 50000
    const int n_dst = in_sizes[1] / IN_FEATS;   // 50000
    const int E     = in_sizes[5];              // 800000

    char* ws = (char*)d_ws;
    float* v    = (float*)(ws);                                                   // 1024 f
    float* el   = (float*)(ws + 4096);                                            // n_src*4
    float* er   = (float*)(ws + 4096 + (size_t)n_src * 16);                       // n_dst*4
    float* ssum = (float*)(ws + 4096 + (size_t)(n_src + n_dst) * 16);             // n_dst*4
    float* wbuf = (float*)(ws + 4096 + (size_t)(n_src + 2 * n_dst) * 16);         // E*4
    float* ft   = (float*)(ws + 4096 + (size_t)(n_src + 2 * n_dst) * 16 + (size_t)E * 16); // n_src*128

    float* out = (float*)d_out;

    (void)hipMemsetAsync(out, 0, (size_t)out_size * sizeof(float), stream);
    (void)hipMemsetAsync(ssum, 0, (size_t)n_dst * NUM_HEADS * sizeof(float), stream);

    compute_v<<<1, 256, 0, stream>>>(W, attn_r, v);
    gemm_ft<<<(n_src + BM - 1) / BM, 256, 0, stream>>>(h_src, W, ft, n_src);
    compute_el<<<(n_src * NUM_HEADS + 255) / 256, 256, 0, stream>>>(ft, attn_l, el, n_src);
    compute_er<<<(n_dst + 3) / 4, 256, 0, stream>>>(h_dst, v, er, n_dst);
    edge_exp<<<((size_t)E * NUM_HEADS + 255) / 256, 256, 0, stream>>>(src_idx, dst_idx, el, er, wbuf, ssum, E);
    edge_norm<<<((size_t)E * NUM_HEADS + 255) / 256, 256, 0, stream>>>(dst_idx, ssum, wbuf, E);
    agg<<<((size_t)E * 64 + 255) / 256, 256, 0, stream>>>(src_idx, dst_idx, ft, wbuf, out, E);
}

// Round 3
// 511.673 us; speedup vs baseline: 1.2136x; 1.2136x over previous
//
#include <hip/hip_runtime.h>

#define IN_FEATS 256
#define OUT_FEATS 32
#define NUM_HEADS 4
#define NHF 128   // NUM_HEADS*OUT_FEATS

#define BM 64
#define BK 32

// v[k*4+h] = sum_f W[k*128 + h*32 + f] * attn_r[h*32 + f]
__global__ void compute_v(const float* __restrict__ W, const float* __restrict__ attn_r,
                          float* __restrict__ v) {
    for (int p = threadIdx.x; p < IN_FEATS * NUM_HEADS; p += blockDim.x) {
        int k = p >> 2, h = p & 3;
        const float* wr = W + (size_t)k * NHF + h * OUT_FEATS;
        const float* ar = attn_r + h * OUT_FEATS;
        float s = 0.f;
        #pragma unroll
        for (int f = 0; f < OUT_FEATS; ++f) s += wr[f] * ar[f];
        v[p] = s;
    }
}

// ft = A @ W : [M,256] x [256,128] -> [M,128], fp32 VALU tiled
__global__ __launch_bounds__(256) void gemm_ft(const float* __restrict__ A,
                                               const float* __restrict__ W,
                                               float* __restrict__ ft, int M) {
    __shared__ float As[BM][BK + 1];
    __shared__ float Bs[BK][NHF];
    const int tid = threadIdx.x;
    const int ty = tid >> 5;
    const int tx = tid & 31;
    const int bm = blockIdx.x * BM;
    float acc[8][4];
    #pragma unroll
    for (int i = 0; i < 8; ++i)
        #pragma unroll
        for (int j = 0; j < 4; ++j) acc[i][j] = 0.f;

    for (int k0 = 0; k0 < IN_FEATS; k0 += BK) {
        for (int t = tid; t < 512; t += 256) {
            int r = t >> 3;
            int c = (t & 7) << 2;
            float4 vv = make_float4(0.f, 0.f, 0.f, 0.f);
            int row = bm + r;
            if (row < M) vv = *(const float4*)(A + (size_t)row * IN_FEATS + k0 + c);
            As[r][c] = vv.x; As[r][c + 1] = vv.y; As[r][c + 2] = vv.z; As[r][c + 3] = vv.w;
        }
        for (int t = tid; t < 1024; t += 256) {
            int r = t >> 5;
            int c = (t & 31) << 2;
            *(float4*)(&Bs[r][c]) = *(const float4*)(W + (size_t)(k0 + r) * NHF + c);
        }
        __syncthreads();
        #pragma unroll
        for (int k = 0; k < BK; ++k) {
            float a[8], b[4];
            #pragma unroll
            for (int i = 0; i < 8; ++i) a[i] = As[ty * 8 + i][k];
            #pragma unroll
            for (int j = 0; j < 4; ++j) b[j] = Bs[k][tx + 32 * j];
            #pragma unroll
            for (int i = 0; i < 8; ++i)
                #pragma unroll
                for (int j = 0; j < 4; ++j) acc[i][j] += a[i] * b[j];
        }
        __syncthreads();
    }
    #pragma unroll
    for (int i = 0; i < 8; ++i) {
        int row = bm + ty * 8 + i;
        if (row < M) {
            float* o = ft + (size_t)row * NHF;
            #pragma unroll
            for (int j = 0; j < 4; ++j) o[tx + 32 * j] = acc[i][j];
        }
    }
}

// el[n*4+h] = sum_f ft[n*128 + h*32 + f] * attn_l[h*32 + f]
__global__ void compute_el(const float* __restrict__ ft, const float* __restrict__ attn_l,
                           float* __restrict__ el, int M) {
    int t = blockIdx.x * blockDim.x + threadIdx.x;
    if (t >= M * NUM_HEADS) return;
    int n = t >> 2, h = t & 3;
    const float4* row = (const float4*)(ft + (size_t)n * NHF + h * OUT_FEATS);
    const float4* al  = (const float4*)(attn_l + h * OUT_FEATS);
    float s = 0.f;
    #pragma unroll
    for (int f = 0; f < 8; ++f) {
        float4 x = row[f], y = al[f];
        s += x.x * y.x + x.y * y.y + x.z * y.z + x.w * y.w;
    }
    el[t] = s;
}

// er[n*4+h] = sum_k h_dst[n*256+k] * v[k*4+h]   (one wave per row)
__global__ __launch_bounds__(256) void compute_er(const float* __restrict__ hdst,
                                                  const float* __restrict__ v,
                                                  float* __restrict__ er, int M) {
    int wid  = (blockIdx.x * blockDim.x + threadIdx.x) >> 6;
    int lane = threadIdx.x & 63;
    if (wid >= M) return;
    const float4 x = *(const float4*)(hdst + (size_t)wid * IN_FEATS + lane * 4);
    const float4* vp = (const float4*)(v + (size_t)lane * 16);
    float4 v0 = vp[0], v1 = vp[1], v2 = vp[2], v3 = vp[3];
    float a0 = x.x * v0.x + x.y * v1.x + x.z * v2.x + x.w * v3.x;
    float a1 = x.x * v0.y + x.y * v1.y + x.z * v2.y + x.w * v3.y;
    float a2 = x.x * v0.z + x.y * v1.z + x.z * v2.z + x.w * v3.z;
    float a3 = x.x * v0.w + x.y * v1.w + x.z * v2.w + x.w * v3.w;
    #pragma unroll
    for (int m = 32; m >= 1; m >>= 1) {
        a0 += __shfl_xor(a0, m, 64);
        a1 += __shfl_xor(a1, m, 64);
        a2 += __shfl_xor(a2, m, 64);
        a3 += __shfl_xor(a3, m, 64);
    }
    if (lane == 0) *(float4*)(er + (size_t)wid * 4) = make_float4(a0, a1, a2, a3);
}

// deg[dst[e]]++
__global__ void hist_dst(const int* __restrict__ dst, int* __restrict__ deg, int E) {
    int e = blockIdx.x * blockDim.x + threadIdx.x;
    if (e < E) atomicAdd(deg + dst[e], 1);
}

// exclusive scan of deg[0..n) -> off[0..n]; also copy to cursor
__global__ __launch_bounds__(1024) void scan_deg(const int* __restrict__ deg,
                                                 int* __restrict__ off,
                                                 int* __restrict__ cursor, int n) {
    __shared__ int part[1024];
    const int t = threadIdx.x;
    const int chunk = (n + 1023) / 1024;
    const int s0 = t * chunk;
    const int s1 = min(s0 + chunk, n);
    int sum = 0;
    for (int i = s0; i < s1; ++i) sum += deg[i];
    part[t] = sum;
    __syncthreads();
    for (int d = 1; d < 1024; d <<= 1) {
        int v = (t >= d) ? part[t - d] : 0;
        __syncthreads();
        part[t] += v;
        __syncthreads();
    }
    int run = (t == 0) ? 0 : part[t - 1];
    for (int i = s0; i < s1; ++i) {
        off[i] = run;
        cursor[i] = run;
        run += deg[i];
    }
    if (t == 1023) off[n] = run;
}

// csr_src[pos] = src[e] for pos = cursor[dst[e]]++
__global__ void scatter_edges(const int* __restrict__ src, const int* __restrict__ dst,
                              int* __restrict__ cursor, int* __restrict__ csr_src, int E) {
    int e = blockIdx.x * blockDim.x + threadIdx.x;
    if (e >= E) return;
    int pos = atomicAdd(cursor + dst[e], 1);
    csr_src[pos] = src[e];
}

// one wave per dst node: pull-aggregate with in-register softmax
__global__ __launch_bounds__(256) void agg_pull(const int* __restrict__ off,
                                                const int* __restrict__ csr_src,
                                                const float* __restrict__ el,
                                                const float* __restrict__ er,
                                                const float* __restrict__ ft,
                                                float* __restrict__ out, int n_dst) {
    int node = (blockIdx.x * blockDim.x + threadIdx.x) >> 6;
    int lane = threadIdx.x & 63;
    if (node >= n_dst) return;
    const int h0 = lane >> 5;       // head for features [0,64)
    const int h1 = 2 + h0;          // head for features [64,128)
    const float er0 = er[(size_t)node * 4 + h0];
    const float er1 = er[(size_t)node * 4 + h1];
    const int start = off[node], end = off[node + 1];
    float acc0 = 0.f, acc1 = 0.f, sw0 = 0.f, sw1 = 0.f;
    for (int k = start; k < end; ++k) {
        int s = csr_src[k];
        float l0 = el[(size_t)s * 4 + h0];
        float l1 = el[(size_t)s * 4 + h1];
        float x0 = l0 + er0; x0 = x0 > 0.f ? x0 : 0.2f * x0;
        float x1 = l1 + er1; x1 = x1 > 0.f ? x1 : 0.2f * x1;
        float w0 = __expf(x0);
        float w1 = __expf(x1);
        const float* fs = ft + (size_t)s * NHF;
        acc0 += fs[lane] * w0;
        acc1 += fs[64 + lane] * w1;
        sw0 += w0;
        sw1 += w1;
    }
    float* o = out + (size_t)node * NHF;
    o[lane]      = (end > start) ? acc0 / sw0 : 0.f;
    o[64 + lane] = (end > start) ? acc1 / sw1 : 0.f;
}

extern "C" void kernel_launch(void* const* d_in, const int* in_sizes, int n_in,
                              void* d_out, int out_size, void* d_ws, size_t ws_size,
                              hipStream_t stream) {
    const float* h_src  = (const float*)d_in[0];
    const float* h_dst  = (const float*)d_in[1];
    const float* W      = (const float*)d_in[2];
    const float* attn_l = (const float*)d_in[3];
    const float* attn_r = (const float*)d_in[4];
    const int* src_idx  = (const int*)d_in[5];
    const int* dst_idx  = (const int*)d_in[6];

    const int n_src = in_sizes[0] / IN_FEATS;   // 50000
    const int n_dst = in_sizes[1] / IN_FEATS;   // 50000
    const int E     = in_sizes[5];              // 800000

    // workspace layout (sizes rounded up generously)
    char* ws = (char*)d_ws;
    size_t o = 0;
    float* v      = (float*)(ws + o); o += 4096;
    float* el     = (float*)(ws + o); o += (size_t)n_src * 4 * sizeof(float);
    float* er     = (float*)(ws + o); o += (size_t)n_dst * 4 * sizeof(float);
    int*   off    = (int*)(ws + o);   o += ((size_t)n_dst + 16) * sizeof(int);
    int*   cursor = (int*)(ws + o);   o += ((size_t)n_dst + 16) * sizeof(int);
    int*   csr_src= (int*)(ws + o);   o += (size_t)E * sizeof(int);
    float* ft     = (float*)(ws + o); o += (size_t)n_src * NHF * sizeof(float);
    int*   deg    = csr_src;          // alias: deg dead before csr_src written

    float* out = (float*)d_out;

    (void)hipMemsetAsync(deg, 0, (size_t)n_dst * sizeof(int), stream);

    compute_v<<<1, 256, 0, stream>>>(W, attn_r, v);
    gemm_ft<<<(n_src + BM - 1) / BM, 256, 0, stream>>>(h_src, W, ft, n_src);
    compute_el<<<(n_src * NUM_HEADS + 255) / 256, 256, 0, stream>>>(ft, attn_l, el, n_src);
    compute_er<<<(n_dst + 3) / 4, 256, 0, stream>>>(h_dst, v, er, n_dst);
    hist_dst<<<(E + 255) / 256, 256, 0, stream>>>(dst_idx, deg, E);
    scan_deg<<<1, 1024, 0, stream>>>(deg, off, cursor, n_dst);
    scatter_edges<<<(E + 255) / 256, 256, 0, stream>>>(src_idx, dst_idx, cursor, csr_src, E);
    agg_pull<<<(n_dst + 3) / 4, 256, 0, stream>>>(off, csr_src, el, er, ft, out, n_dst);
}

// Round 4
// 409.952 us; speedup vs baseline: 1.5148x; 1.2481x over previous
//
#include <hip/hip_runtime.h>

#define IN_FEATS 256
#define OUT_FEATS 32
#define NUM_HEADS 4
#define NHF 128   // NUM_HEADS*OUT_FEATS

#define BM 64
#define BK 32

// v[k*4+h] = sum_f W[k*128 + h*32 + f] * attn_r[h*32 + f]
__global__ void compute_v(const float* __restrict__ W, const float* __restrict__ attn_r,
                          float* __restrict__ v) {
    for (int p = threadIdx.x; p < IN_FEATS * NUM_HEADS; p += blockDim.x) {
        int k = p >> 2, h = p & 3;
        const float* wr = W + (size_t)k * NHF + h * OUT_FEATS;
        const float* ar = attn_r + h * OUT_FEATS;
        float s = 0.f;
        #pragma unroll
        for (int f = 0; f < OUT_FEATS; ++f) s += wr[f] * ar[f];
        v[p] = s;
    }
}

// ft = A @ W : [M,256] x [256,128] -> [M,128], fp32 VALU tiled
__global__ __launch_bounds__(256) void gemm_ft(const float* __restrict__ A,
                                               const float* __restrict__ W,
                                               float* __restrict__ ft, int M) {
    __shared__ float As[BM][BK + 1];
    __shared__ float Bs[BK][NHF];
    const int tid = threadIdx.x;
    const int ty = tid >> 5;
    const int tx = tid & 31;
    const int bm = blockIdx.x * BM;
    float acc[8][4];
    #pragma unroll
    for (int i = 0; i < 8; ++i)
        #pragma unroll
        for (int j = 0; j < 4; ++j) acc[i][j] = 0.f;

    for (int k0 = 0; k0 < IN_FEATS; k0 += BK) {
        for (int t = tid; t < 512; t += 256) {
            int r = t >> 3;
            int c = (t & 7) << 2;
            float4 vv = make_float4(0.f, 0.f, 0.f, 0.f);
            int row = bm + r;
            if (row < M) vv = *(const float4*)(A + (size_t)row * IN_FEATS + k0 + c);
            As[r][c] = vv.x; As[r][c + 1] = vv.y; As[r][c + 2] = vv.z; As[r][c + 3] = vv.w;
        }
        for (int t = tid; t < 1024; t += 256) {
            int r = t >> 5;
            int c = (t & 31) << 2;
            *(float4*)(&Bs[r][c]) = *(const float4*)(W + (size_t)(k0 + r) * NHF + c);
        }
        __syncthreads();
        #pragma unroll
        for (int k = 0; k < BK; ++k) {
            float a[8], b[4];
            #pragma unroll
            for (int i = 0; i < 8; ++i) a[i] = As[ty * 8 + i][k];
            #pragma unroll
            for (int j = 0; j < 4; ++j) b[j] = Bs[k][tx + 32 * j];
            #pragma unroll
            for (int i = 0; i < 8; ++i)
                #pragma unroll
                for (int j = 0; j < 4; ++j) acc[i][j] += a[i] * b[j];
        }
        __syncthreads();
    }
    #pragma unroll
    for (int i = 0; i < 8; ++i) {
        int row = bm + ty * 8 + i;
        if (row < M) {
            float* o = ft + (size_t)row * NHF;
            #pragma unroll
            for (int j = 0; j < 4; ++j) o[tx + 32 * j] = acc[i][j];
        }
    }
}

// el[n*4+h] = sum_f ft[n*128 + h*32 + f] * attn_l[h*32 + f]
__global__ void compute_el(const float* __restrict__ ft, const float* __restrict__ attn_l,
                           float* __restrict__ el, int M) {
    int t = blockIdx.x * blockDim.x + threadIdx.x;
    if (t >= M * NUM_HEADS) return;
    int n = t >> 2, h = t & 3;
    const float4* row = (const float4*)(ft + (size_t)n * NHF + h * OUT_FEATS);
    const float4* al  = (const float4*)(attn_l + h * OUT_FEATS);
    float s = 0.f;
    #pragma unroll
    for (int f = 0; f < 8; ++f) {
        float4 x = row[f], y = al[f];
        s += x.x * y.x + x.y * y.y + x.z * y.z + x.w * y.w;
    }
    el[t] = s;
}

// er[n*4+h] = sum_k h_dst[n*256+k] * v[k*4+h]   (one wave per row)
__global__ __launch_bounds__(256) void compute_er(const float* __restrict__ hdst,
                                                  const float* __restrict__ v,
                                                  float* __restrict__ er, int M) {
    int wid  = (blockIdx.x * blockDim.x + threadIdx.x) >> 6;
    int lane = threadIdx.x & 63;
    if (wid >= M) return;
    const float4 x = *(const float4*)(hdst + (size_t)wid * IN_FEATS + lane * 4);
    const float4* vp = (const float4*)(v + (size_t)lane * 16);
    float4 v0 = vp[0], v1 = vp[1], v2 = vp[2], v3 = vp[3];
    float a0 = x.x * v0.x + x.y * v1.x + x.z * v2.x + x.w * v3.x;
    float a1 = x.x * v0.y + x.y * v1.y + x.z * v2.y + x.w * v3.y;
    float a2 = x.x * v0.z + x.y * v1.z + x.z * v2.z + x.w * v3.z;
    float a3 = x.x * v0.w + x.y * v1.w + x.z * v2.w + x.w * v3.w;
    #pragma unroll
    for (int m = 32; m >= 1; m >>= 1) {
        a0 += __shfl_xor(a0, m, 64);
        a1 += __shfl_xor(a1, m, 64);
        a2 += __shfl_xor(a2, m, 64);
        a3 += __shfl_xor(a3, m, 64);
    }
    if (lane == 0) *(float4*)(er + (size_t)wid * 4) = make_float4(a0, a1, a2, a3);
}

// deg[dst[e]]++
__global__ void hist_dst(const int* __restrict__ dst, int* __restrict__ deg, int E) {
    int e = blockIdx.x * blockDim.x + threadIdx.x;
    if (e < E) atomicAdd(deg + dst[e], 1);
}

// ---- hierarchical exclusive scan of deg[0..n) -> off[0..n], cursor ----
// level 1: per-block (256 elems) sums
__global__ __launch_bounds__(256) void scan_partial(const int* __restrict__ deg,
                                                    int* __restrict__ partial, int n) {
    __shared__ int red[4];
    int i = blockIdx.x * 256 + threadIdx.x;
    int v = (i < n) ? deg[i] : 0;
    #pragma unroll
    for (int m = 32; m >= 1; m >>= 1) v += __shfl_xor(v, m, 64);
    int wave = threadIdx.x >> 6, lane = threadIdx.x & 63;
    if (lane == 0) red[wave] = v;
    __syncthreads();
    if (threadIdx.x == 0) partial[blockIdx.x] = red[0] + red[1] + red[2] + red[3];
}

// level 2: single block scans <=256 partials -> exclusive base; writes off[n]=total
__global__ __launch_bounds__(256) void scan_top(const int* __restrict__ partial,
                                                int* __restrict__ base,
                                                int* __restrict__ off, int nblk, int n) {
    __shared__ int s[256];
    int t = threadIdx.x;
    int v = (t < nblk) ? partial[t] : 0;
    s[t] = v;
    __syncthreads();
    #pragma unroll
    for (int d = 1; d < 256; d <<= 1) {
        int x = (t >= d) ? s[t - d] : 0;
        __syncthreads();
        s[t] += x;
        __syncthreads();
    }
    if (t < nblk) base[t] = s[t] - v;   // exclusive prefix
    if (t == 255) off[n] = s[255];      // total
}

// level 3: per-block local exclusive scan + base, write off & cursor
__global__ __launch_bounds__(256) void scan_final(const int* __restrict__ deg,
                                                  const int* __restrict__ base,
                                                  int* __restrict__ off,
                                                  int* __restrict__ cursor, int n) {
    __shared__ int s[256];
    int i = blockIdx.x * 256 + threadIdx.x;
    int t = threadIdx.x;
    int v = (i < n) ? deg[i] : 0;
    s[t] = v;
    __syncthreads();
    #pragma unroll
    for (int d = 1; d < 256; d <<= 1) {
        int x = (t >= d) ? s[t - d] : 0;
        __syncthreads();
        s[t] += x;
        __syncthreads();
    }
    int ex = s[t] - v + base[blockIdx.x];
    if (i < n) { off[i] = ex; cursor[i] = ex; }
}

// csr_src[pos] = src[e] for pos = cursor[dst[e]]++
__global__ void scatter_edges(const int* __restrict__ src, const int* __restrict__ dst,
                              int* __restrict__ cursor, int* __restrict__ csr_src, int E) {
    int e = blockIdx.x * blockDim.x + threadIdx.x;
    if (e >= E) return;
    int pos = atomicAdd(cursor + dst[e], 1);
    csr_src[pos] = src[e];
}

// one wave per dst node: pull-aggregate with in-register softmax
__global__ __launch_bounds__(256) void agg_pull(const int* __restrict__ off,
                                                const int* __restrict__ csr_src,
                                                const float* __restrict__ el,
                                                const float* __restrict__ er,
                                                const float* __restrict__ ft,
                                                float* __restrict__ out, int n_dst) {
    int node = (blockIdx.x * blockDim.x + threadIdx.x) >> 6;
    int lane = threadIdx.x & 63;
    if (node >= n_dst) return;
    const int h0 = lane >> 5;       // head for features [0,64)
    const int h1 = 2 + h0;          // head for features [64,128)
    const float er0 = er[(size_t)node * 4 + h0];
    const float er1 = er[(size_t)node * 4 + h1];
    const int start = off[node], end = off[node + 1];
    float acc0 = 0.f, acc1 = 0.f, sw0 = 0.f, sw1 = 0.f;
    for (int k = start; k < end; ++k) {
        int s = csr_src[k];
        float l0 = el[(size_t)s * 4 + h0];
        float l1 = el[(size_t)s * 4 + h1];
        float x0 = l0 + er0; x0 = x0 > 0.f ? x0 : 0.2f * x0;
        float x1 = l1 + er1; x1 = x1 > 0.f ? x1 : 0.2f * x1;
        float w0 = __expf(x0);
        float w1 = __expf(x1);
        const float* fs = ft + (size_t)s * NHF;
        acc0 += fs[lane] * w0;
        acc1 += fs[64 + lane] * w1;
        sw0 += w0;
        sw1 += w1;
    }
    float* o = out + (size_t)node * NHF;
    o[lane]      = (end > start) ? acc0 / sw0 : 0.f;
    o[64 + lane] = (end > start) ? acc1 / sw1 : 0.f;
}

extern "C" void kernel_launch(void* const* d_in, const int* in_sizes, int n_in,
                              void* d_out, int out_size, void* d_ws, size_t ws_size,
                              hipStream_t stream) {
    const float* h_src  = (const float*)d_in[0];
    const float* h_dst  = (const float*)d_in[1];
    const float* W      = (const float*)d_in[2];
    const float* attn_l = (const float*)d_in[3];
    const float* attn_r = (const float*)d_in[4];
    const int* src_idx  = (const int*)d_in[5];
    const int* dst_idx  = (const int*)d_in[6];

    const int n_src = in_sizes[0] / IN_FEATS;   // 50000
    const int n_dst = in_sizes[1] / IN_FEATS;   // 50000
    const int E     = in_sizes[5];              // 800000

    const int nblk = (n_dst + 255) / 256;       // 196 (<=256 required by scan_top)

    // workspace layout
    char* ws = (char*)d_ws;
    size_t o = 0;
    float* v      = (float*)(ws + o); o += 4096;
    float* el     = (float*)(ws + o); o += (size_t)n_src * 4 * sizeof(float);
    float* er     = (float*)(ws + o); o += (size_t)n_dst * 4 * sizeof(float);
    int*   off    = (int*)(ws + o);   o += ((size_t)n_dst + 16) * sizeof(int);
    int*   cursor = (int*)(ws + o);   o += ((size_t)n_dst + 16) * sizeof(int);
    int*   partial= (int*)(ws + o);   o += 256 * sizeof(int);
    int*   base   = (int*)(ws + o);   o += 256 * sizeof(int);
    int*   csr_src= (int*)(ws + o);   o += (size_t)E * sizeof(int);
    float* ft     = (float*)(ws + o); o += (size_t)n_src * NHF * sizeof(float);
    int*   deg    = csr_src;          // alias: deg dead before csr_src written

    float* out = (float*)d_out;

    (void)hipMemsetAsync(deg, 0, (size_t)n_dst * sizeof(int), stream);

    compute_v<<<1, 256, 0, stream>>>(W, attn_r, v);
    gemm_ft<<<(n_src + BM - 1) / BM, 256, 0, stream>>>(h_src, W, ft, n_src);
    compute_el<<<(n_src * NUM_HEADS + 255) / 256, 256, 0, stream>>>(ft, attn_l, el, n_src);
    compute_er<<<(n_dst + 3) / 4, 256, 0, stream>>>(h_dst, v, er, n_dst);
    hist_dst<<<(E + 255) / 256, 256, 0, stream>>>(dst_idx, deg, E);
    scan_partial<<<nblk, 256, 0, stream>>>(deg, partial, n_dst);
    scan_top<<<1, 256, 0, stream>>>(partial, base, off, nblk, n_dst);
    scan_final<<<nblk, 256, 0, stream>>>(deg, base, off, cursor, n_dst);
    scatter_edges<<<(E + 255) / 256, 256, 0, stream>>>(src_idx, dst_idx, cursor, csr_src, E);
    agg_pull<<<(n_dst + 3) / 4, 256, 0, stream>>>(off, csr_src, el, er, ft, out, n_dst);
}

// Round 5
// 351.825 us; speedup vs baseline: 1.7650x; 1.1652x over previous
//
#include <hip/hip_runtime.h>

#define IN_FEATS 256
#define OUT_FEATS 32
#define NUM_HEADS 4
#define NHF 128   // NUM_HEADS*OUT_FEATS

typedef __attribute__((ext_vector_type(8))) short short8;
typedef __attribute__((ext_vector_type(4))) float f32x4;

__device__ inline unsigned short f2bf(float f) {
    unsigned int u = __builtin_bit_cast(unsigned int, f);
    u = (u + 0x7fff + ((u >> 16) & 1)) >> 16;   // RNE
    return (unsigned short)u;
}
__device__ inline float bfhi2f(unsigned int packed_hi) {   // bits already in [31:16]
    return __builtin_bit_cast(float, packed_hi);
}

// prep: blocks 0..127 transpose W -> Wt bf16 [128][256]; block 128 computes
// v[k*4+h] = sum_f W[k*128 + h*32 + f] * attn_r[h*32 + f]
__global__ __launch_bounds__(256) void prep(const float* __restrict__ W,
                                            const float* __restrict__ attn_r,
                                            float* __restrict__ v,
                                            unsigned short* __restrict__ Wt) {
    if (blockIdx.x < 128) {
        int n = blockIdx.x;
        int k = threadIdx.x;
        Wt[n * 256 + k] = f2bf(W[(size_t)k * NHF + n]);
    } else {
        for (int p = threadIdx.x; p < IN_FEATS * NUM_HEADS; p += 256) {
            int k = p >> 2, h = p & 3;
            const float* wr = W + (size_t)k * NHF + h * OUT_FEATS;
            const float* ar = attn_r + h * OUT_FEATS;
            float s = 0.f;
            #pragma unroll
            for (int f = 0; f < OUT_FEATS; ++f) s += wr[f] * ar[f];
            v[p] = s;
        }
    }
}

// ft16 = bf16(A @ W), el fused. One wave per 16 rows, MFMA 16x16x32 bf16.
__global__ __launch_bounds__(256) void gemm_el(const float* __restrict__ A,
                                               const unsigned short* __restrict__ Wt,
                                               const float* __restrict__ attn_l,
                                               unsigned short* __restrict__ ft16,
                                               float* __restrict__ el, int M) {
    const int wave = threadIdx.x >> 6;
    const int lane = threadIdx.x & 63;
    const int quad = lane >> 4;
    const int mc   = lane & 15;
    const int row_base = blockIdx.x * 64 + wave * 16;

    // attn_l regs: al[t] = attn_l[(t>>1)*32 + (t&1)*16 + mc]
    float al[8];
    #pragma unroll
    for (int t = 0; t < 8; ++t) al[t] = attn_l[(t >> 1) * 32 + (t & 1) * 16 + mc];

    const int rowA = min(row_base + mc, M - 1);
    const float* arow = A + (size_t)rowA * IN_FEATS;

    f32x4 acc[8];
    #pragma unroll
    for (int t = 0; t < 8; ++t) acc[t] = (f32x4){0.f, 0.f, 0.f, 0.f};

    #pragma unroll
    for (int k0 = 0; k0 < IN_FEATS; k0 += 32) {
        const float4 a0 = *(const float4*)(arow + k0 + quad * 8);
        const float4 a1 = *(const float4*)(arow + k0 + quad * 8 + 4);
        short8 af;
        af[0] = (short)f2bf(a0.x); af[1] = (short)f2bf(a0.y);
        af[2] = (short)f2bf(a0.z); af[3] = (short)f2bf(a0.w);
        af[4] = (short)f2bf(a1.x); af[5] = (short)f2bf(a1.y);
        af[6] = (short)f2bf(a1.z); af[7] = (short)f2bf(a1.w);
        #pragma unroll
        for (int t = 0; t < 8; ++t) {
            const int n = t * 16 + mc;
            const short8 bf = *(const short8*)(Wt + (size_t)n * IN_FEATS + k0 + quad * 8);
            acc[t] = __builtin_amdgcn_mfma_f32_16x16x32_bf16(af, bf, acc[t], 0, 0, 0);
        }
    }

    // el partials from fp32 accs: elp[v][h]
    float elp[4][4];
    #pragma unroll
    for (int v = 0; v < 4; ++v)
        #pragma unroll
        for (int h = 0; h < 4; ++h) elp[v][h] = 0.f;
    #pragma unroll
    for (int v = 0; v < 4; ++v)
        #pragma unroll
        for (int t = 0; t < 8; ++t) elp[v][t >> 1] += acc[t][v] * al[t];
    // reduce across the 16 lanes of each quad
    #pragma unroll
    for (int v = 0; v < 4; ++v)
        #pragma unroll
        for (int h = 0; h < 4; ++h) {
            #pragma unroll
            for (int d = 1; d < 16; d <<= 1)
                elp[v][h] += __shfl_xor(elp[v][h], d, 64);
        }

    #pragma unroll
    for (int v = 0; v < 4; ++v) {
        const int rg = row_base + quad * 4 + v;
        if (rg < M) {
            unsigned short* o = ft16 + (size_t)rg * NHF;
            #pragma unroll
            for (int t = 0; t < 8; ++t) o[t * 16 + mc] = f2bf(acc[t][v]);
            if (mc < 4) {
                float ev = (mc == 0) ? elp[v][0] : (mc == 1) ? elp[v][1]
                         : (mc == 2) ? elp[v][2] : elp[v][3];
                el[(size_t)rg * 4 + mc] = ev;
            }
        }
    }
}

// er[n*4+h] = sum_k h_dst[n*256+k] * v[k*4+h]   (one wave per row)
__global__ __launch_bounds__(256) void compute_er(const float* __restrict__ hdst,
                                                  const float* __restrict__ v,
                                                  float* __restrict__ er, int M) {
    int wid  = (blockIdx.x * blockDim.x + threadIdx.x) >> 6;
    int lane = threadIdx.x & 63;
    if (wid >= M) return;
    const float4 x = *(const float4*)(hdst + (size_t)wid * IN_FEATS + lane * 4);
    const float4* vp = (const float4*)(v + (size_t)lane * 16);
    float4 v0 = vp[0], v1 = vp[1], v2 = vp[2], v3 = vp[3];
    float a0 = x.x * v0.x + x.y * v1.x + x.z * v2.x + x.w * v3.x;
    float a1 = x.x * v0.y + x.y * v1.y + x.z * v2.y + x.w * v3.y;
    float a2 = x.x * v0.z + x.y * v1.z + x.z * v2.z + x.w * v3.z;
    float a3 = x.x * v0.w + x.y * v1.w + x.z * v2.w + x.w * v3.w;
    #pragma unroll
    for (int m = 32; m >= 1; m >>= 1) {
        a0 += __shfl_xor(a0, m, 64);
        a1 += __shfl_xor(a1, m, 64);
        a2 += __shfl_xor(a2, m, 64);
        a3 += __shfl_xor(a3, m, 64);
    }
    if (lane == 0) *(float4*)(er + (size_t)wid * 4) = make_float4(a0, a1, a2, a3);
}

// deg[dst[e]]++
__global__ void hist_dst(const int* __restrict__ dst, int* __restrict__ deg, int E) {
    int e = blockIdx.x * blockDim.x + threadIdx.x;
    if (e < E) atomicAdd(deg + dst[e], 1);
}

// ---- hierarchical exclusive scan ----
__global__ __launch_bounds__(256) void scan_partial(const int* __restrict__ deg,
                                                    int* __restrict__ partial, int n) {
    __shared__ int red[4];
    int i = blockIdx.x * 256 + threadIdx.x;
    int v = (i < n) ? deg[i] : 0;
    #pragma unroll
    for (int m = 32; m >= 1; m >>= 1) v += __shfl_xor(v, m, 64);
    int wave = threadIdx.x >> 6, lane = threadIdx.x & 63;
    if (lane == 0) red[wave] = v;
    __syncthreads();
    if (threadIdx.x == 0) partial[blockIdx.x] = red[0] + red[1] + red[2] + red[3];
}

__global__ __launch_bounds__(256) void scan_top(const int* __restrict__ partial,
                                                int* __restrict__ base,
                                                int* __restrict__ off, int nblk, int n) {
    __shared__ int s[256];
    int t = threadIdx.x;
    int v = (t < nblk) ? partial[t] : 0;
    s[t] = v;
    __syncthreads();
    #pragma unroll
    for (int d = 1; d < 256; d <<= 1) {
        int x = (t >= d) ? s[t - d] : 0;
        __syncthreads();
        s[t] += x;
        __syncthreads();
    }
    if (t < nblk) base[t] = s[t] - v;
    if (t == 255) off[n] = s[255];
}

__global__ __launch_bounds__(256) void scan_final(const int* __restrict__ deg,
                                                  const int* __restrict__ base,
                                                  int* __restrict__ off,
                                                  int* __restrict__ cursor, int n) {
    __shared__ int s[256];
    int i = blockIdx.x * 256 + threadIdx.x;
    int t = threadIdx.x;
    int v = (i < n) ? deg[i] : 0;
    s[t] = v;
    __syncthreads();
    #pragma unroll
    for (int d = 1; d < 256; d <<= 1) {
        int x = (t >= d) ? s[t - d] : 0;
        __syncthreads();
        s[t] += x;
        __syncthreads();
    }
    int ex = s[t] - v + base[blockIdx.x];
    if (i < n) { off[i] = ex; cursor[i] = ex; }
}

// csr_src[pos] = src[e] for pos = cursor[dst[e]]++
__global__ void scatter_edges(const int* __restrict__ src, const int* __restrict__ dst,
                              int* __restrict__ cursor, int* __restrict__ csr_src, int E) {
    int e = blockIdx.x * blockDim.x + threadIdx.x;
    if (e >= E) return;
    int pos = atomicAdd(cursor + dst[e], 1);
    csr_src[pos] = src[e];
}

// one wave per dst node; lane owns cols 2*lane, 2*lane+1 (head = lane>>4)
__global__ __launch_bounds__(256) void agg_pull(const int* __restrict__ off,
                                                const int* __restrict__ csr_src,
                                                const float* __restrict__ el,
                                                const float* __restrict__ er,
                                                const unsigned int* __restrict__ ft16p,
                                                float* __restrict__ out, int n_dst) {
    int node = (blockIdx.x * blockDim.x + threadIdx.x) >> 6;
    int lane = threadIdx.x & 63;
    if (node >= n_dst) return;
    const int h = lane >> 4;
    const float er_h = er[(size_t)node * 4 + h];
    const int start = off[node], end = off[node + 1];
    float a0 = 0.f, a1 = 0.f, sw = 0.f;
    for (int k = start; k < end; ++k) {
        int s = csr_src[k];
        float x = el[(size_t)s * 4 + h] + er_h;
        x = x > 0.f ? x : 0.2f * x;
        float w = __expf(x);
        unsigned int p = ft16p[(size_t)s * 64 + lane];   // 2 bf16, coalesced 256B/wave
        a0 += bfhi2f(p << 16) * w;
        a1 += bfhi2f(p & 0xffff0000u) * w;
        sw += w;
    }
    float2 r;
    r.x = (end > start) ? a0 / sw : 0.f;
    r.y = (end > start) ? a1 / sw : 0.f;
    *(float2*)(out + (size_t)node * NHF + 2 * lane) = r;
}

extern "C" void kernel_launch(void* const* d_in, const int* in_sizes, int n_in,
                              void* d_out, int out_size, void* d_ws, size_t ws_size,
                              hipStream_t stream) {
    const float* h_src  = (const float*)d_in[0];
    const float* h_dst  = (const float*)d_in[1];
    const float* W      = (const float*)d_in[2];
    const float* attn_l = (const float*)d_in[3];
    const float* attn_r = (const float*)d_in[4];
    const int* src_idx  = (const int*)d_in[5];
    const int* dst_idx  = (const int*)d_in[6];

    const int n_src = in_sizes[0] / IN_FEATS;   // 50000
    const int n_dst = in_sizes[1] / IN_FEATS;   // 50000
    const int E     = in_sizes[5];              // 800000

    const int nblk = (n_dst + 255) / 256;       // 196 (<=256 required by scan_top)

    // workspace layout
    char* ws = (char*)d_ws;
    size_t o = 0;
    float* v       = (float*)(ws + o); o += 4096;
    float* el      = (float*)(ws + o); o += (size_t)n_src * 4 * sizeof(float);
    float* er      = (float*)(ws + o); o += (size_t)n_dst * 4 * sizeof(float);
    int*   off     = (int*)(ws + o);   o += ((size_t)n_dst + 16) * sizeof(int);
    int*   cursor  = (int*)(ws + o);   o += ((size_t)n_dst + 16) * sizeof(int);
    int*   partial = (int*)(ws + o);   o += 256 * sizeof(int);
    int*   base    = (int*)(ws + o);   o += 256 * sizeof(int);
    unsigned short* Wt = (unsigned short*)(ws + o); o += (size_t)NHF * IN_FEATS * sizeof(unsigned short);
    int*   csr_src = (int*)(ws + o);   o += (size_t)E * sizeof(int);
    unsigned short* ft16 = (unsigned short*)(ws + o); o += (size_t)n_src * NHF * sizeof(unsigned short);
    int*   deg     = csr_src;          // alias: deg dead before csr_src written

    float* out = (float*)d_out;

    (void)hipMemsetAsync(deg, 0, (size_t)n_dst * sizeof(int), stream);

    prep<<<129, 256, 0, stream>>>(W, attn_r, v, Wt);
    gemm_el<<<(n_src + 63) / 64, 256, 0, stream>>>(h_src, Wt, attn_l, ft16, el, n_src);
    compute_er<<<(n_dst + 3) / 4, 256, 0, stream>>>(h_dst, v, er, n_dst);
    hist_dst<<<(E + 255) / 256, 256, 0, stream>>>(dst_idx, deg, E);
    scan_partial<<<nblk, 256, 0, stream>>>(deg, partial, n_dst);
    scan_top<<<1, 256, 0, stream>>>(partial, base, off, nblk, n_dst);
    scan_final<<<nblk, 256, 0, stream>>>(deg, base, off, cursor, n_dst);
    scatter_edges<<<(E + 255) / 256, 256, 0, stream>>>(src_idx, dst_idx, cursor, csr_src, E);
    agg_pull<<<(n_dst + 3) / 4, 256, 0, stream>>>(off, csr_src, el, er, (const unsigned int*)ft16, out, n_dst);
}

// Round 6
// 318.201 us; speedup vs baseline: 1.9515x; 1.1057x over previous
//
#include <hip/hip_runtime.h>

#define IN_FEATS 256
#define OUT_FEATS 32
#define NUM_HEADS 4
#define NHF 128   // NUM_HEADS*OUT_FEATS

typedef __attribute__((ext_vector_type(8))) short short8;
typedef __attribute__((ext_vector_type(4))) float f32x4;

__device__ inline unsigned short f2bf(float f) {
    unsigned int u = __builtin_bit_cast(unsigned int, f);
    u = (u + 0x7fff + ((u >> 16) & 1)) >> 16;   // RNE
    return (unsigned short)u;
}
__device__ inline float bfhi2f(unsigned int packed_hi) {   // bits already in [31:16]
    return __builtin_bit_cast(float, packed_hi);
}

// prep: blocks 0..127 transpose W -> Wt bf16 [128][256]; block 128 computes
// v[k*4+h] = sum_f W[k*128 + h*32 + f] * attn_r[h*32 + f]
__global__ __launch_bounds__(256) void prep(const float* __restrict__ W,
                                            const float* __restrict__ attn_r,
                                            float* __restrict__ v,
                                            unsigned short* __restrict__ Wt) {
    if (blockIdx.x < 128) {
        int n = blockIdx.x;
        int k = threadIdx.x;
        Wt[n * 256 + k] = f2bf(W[(size_t)k * NHF + n]);
    } else {
        for (int p = threadIdx.x; p < IN_FEATS * NUM_HEADS; p += 256) {
            int k = p >> 2, h = p & 3;
            const float* wr = W + (size_t)k * NHF + h * OUT_FEATS;
            const float* ar = attn_r + h * OUT_FEATS;
            float s = 0.f;
            #pragma unroll
            for (int f = 0; f < OUT_FEATS; ++f) s += wr[f] * ar[f];
            v[p] = s;
        }
    }
}

// ft16 = bf16(A @ W), el fused. One wave per 16 rows, MFMA 16x16x32 bf16.
__global__ __launch_bounds__(256) void gemm_el(const float* __restrict__ A,
                                               const unsigned short* __restrict__ Wt,
                                               const float* __restrict__ attn_l,
                                               unsigned short* __restrict__ ft16,
                                               float* __restrict__ el, int M) {
    const int wave = threadIdx.x >> 6;
    const int lane = threadIdx.x & 63;
    const int quad = lane >> 4;
    const int mc   = lane & 15;
    const int row_base = blockIdx.x * 64 + wave * 16;

    // attn_l regs: al[t] = attn_l[(t>>1)*32 + (t&1)*16 + mc]
    float al[8];
    #pragma unroll
    for (int t = 0; t < 8; ++t) al[t] = attn_l[(t >> 1) * 32 + (t & 1) * 16 + mc];

    const int rowA = min(row_base + mc, M - 1);
    const float* arow = A + (size_t)rowA * IN_FEATS;

    f32x4 acc[8];
    #pragma unroll
    for (int t = 0; t < 8; ++t) acc[t] = (f32x4){0.f, 0.f, 0.f, 0.f};

    #pragma unroll
    for (int k0 = 0; k0 < IN_FEATS; k0 += 32) {
        const float4 a0 = *(const float4*)(arow + k0 + quad * 8);
        const float4 a1 = *(const float4*)(arow + k0 + quad * 8 + 4);
        short8 af;
        af[0] = (short)f2bf(a0.x); af[1] = (short)f2bf(a0.y);
        af[2] = (short)f2bf(a0.z); af[3] = (short)f2bf(a0.w);
        af[4] = (short)f2bf(a1.x); af[5] = (short)f2bf(a1.y);
        af[6] = (short)f2bf(a1.z); af[7] = (short)f2bf(a1.w);
        #pragma unroll
        for (int t = 0; t < 8; ++t) {
            const int n = t * 16 + mc;
            const short8 bf = *(const short8*)(Wt + (size_t)n * IN_FEATS + k0 + quad * 8);
            acc[t] = __builtin_amdgcn_mfma_f32_16x16x32_bf16(af, bf, acc[t], 0, 0, 0);
        }
    }

    // el partials from fp32 accs: elp[v][h]
    float elp[4][4];
    #pragma unroll
    for (int v = 0; v < 4; ++v)
        #pragma unroll
        for (int h = 0; h < 4; ++h) elp[v][h] = 0.f;
    #pragma unroll
    for (int v = 0; v < 4; ++v)
        #pragma unroll
        for (int t = 0; t < 8; ++t) elp[v][t >> 1] += acc[t][v] * al[t];
    // reduce across the 16 lanes of each quad
    #pragma unroll
    for (int v = 0; v < 4; ++v)
        #pragma unroll
        for (int h = 0; h < 4; ++h) {
            #pragma unroll
            for (int d = 1; d < 16; d <<= 1)
                elp[v][h] += __shfl_xor(elp[v][h], d, 64);
        }

    #pragma unroll
    for (int v = 0; v < 4; ++v) {
        const int rg = row_base + quad * 4 + v;
        if (rg < M) {
            unsigned short* o = ft16 + (size_t)rg * NHF;
            #pragma unroll
            for (int t = 0; t < 8; ++t) o[t * 16 + mc] = f2bf(acc[t][v]);
            if (mc < 4) {
                float ev = (mc == 0) ? elp[v][0] : (mc == 1) ? elp[v][1]
                         : (mc == 2) ? elp[v][2] : elp[v][3];
                el[(size_t)rg * 4 + mc] = ev;
            }
        }
    }
}

// er[n*4+h] = sum_k h_dst[n*256+k] * v[k*4+h]   (one wave per row)
__global__ __launch_bounds__(256) void compute_er(const float* __restrict__ hdst,
                                                  const float* __restrict__ v,
                                                  float* __restrict__ er, int M) {
    int wid  = (blockIdx.x * blockDim.x + threadIdx.x) >> 6;
    int lane = threadIdx.x & 63;
    if (wid >= M) return;
    const float4 x = *(const float4*)(hdst + (size_t)wid * IN_FEATS + lane * 4);
    const float4* vp = (const float4*)(v + (size_t)lane * 16);
    float4 v0 = vp[0], v1 = vp[1], v2 = vp[2], v3 = vp[3];
    float a0 = x.x * v0.x + x.y * v1.x + x.z * v2.x + x.w * v3.x;
    float a1 = x.x * v0.y + x.y * v1.y + x.z * v2.y + x.w * v3.y;
    float a2 = x.x * v0.z + x.y * v1.z + x.z * v2.z + x.w * v3.z;
    float a3 = x.x * v0.w + x.y * v1.w + x.z * v2.w + x.w * v3.w;
    #pragma unroll
    for (int m = 32; m >= 1; m >>= 1) {
        a0 += __shfl_xor(a0, m, 64);
        a1 += __shfl_xor(a1, m, 64);
        a2 += __shfl_xor(a2, m, 64);
        a3 += __shfl_xor(a3, m, 64);
    }
    if (lane == 0) *(float4*)(er + (size_t)wid * 4) = make_float4(a0, a1, a2, a3);
}

// deg[dst[e]]++
__global__ void hist_dst(const int* __restrict__ dst, int* __restrict__ deg, int E) {
    int e = blockIdx.x * blockDim.x + threadIdx.x;
    if (e < E) atomicAdd(deg + dst[e], 1);
}

// ---- hierarchical exclusive scan ----
__global__ __launch_bounds__(256) void scan_partial(const int* __restrict__ deg,
                                                    int* __restrict__ partial, int n) {
    __shared__ int red[4];
    int i = blockIdx.x * 256 + threadIdx.x;
    int v = (i < n) ? deg[i] : 0;
    #pragma unroll
    for (int m = 32; m >= 1; m >>= 1) v += __shfl_xor(v, m, 64);
    int wave = threadIdx.x >> 6, lane = threadIdx.x & 63;
    if (lane == 0) red[wave] = v;
    __syncthreads();
    if (threadIdx.x == 0) partial[blockIdx.x] = red[0] + red[1] + red[2] + red[3];
}

__global__ __launch_bounds__(256) void scan_top(const int* __restrict__ partial,
                                                int* __restrict__ base,
                                                int* __restrict__ off, int nblk, int n) {
    __shared__ int s[256];
    int t = threadIdx.x;
    int v = (t < nblk) ? partial[t] : 0;
    s[t] = v;
    __syncthreads();
    #pragma unroll
    for (int d = 1; d < 256; d <<= 1) {
        int x = (t >= d) ? s[t - d] : 0;
        __syncthreads();
        s[t] += x;
        __syncthreads();
    }
    if (t < nblk) base[t] = s[t] - v;
    if (t == 255) off[n] = s[255];
}

__global__ __launch_bounds__(256) void scan_final(const int* __restrict__ deg,
                                                  const int* __restrict__ base,
                                                  int* __restrict__ off,
                                                  int* __restrict__ cursor, int n) {
    __shared__ int s[256];
    int i = blockIdx.x * 256 + threadIdx.x;
    int t = threadIdx.x;
    int v = (i < n) ? deg[i] : 0;
    s[t] = v;
    __syncthreads();
    #pragma unroll
    for (int d = 1; d < 256; d <<= 1) {
        int x = (t >= d) ? s[t - d] : 0;
        __syncthreads();
        s[t] += x;
        __syncthreads();
    }
    int ex = s[t] - v + base[blockIdx.x];
    if (i < n) { off[i] = ex; cursor[i] = ex; }
}

// csr_src[pos] = src[e] for pos = cursor[dst[e]]++
__global__ void scatter_edges(const int* __restrict__ src, const int* __restrict__ dst,
                              int* __restrict__ cursor, int* __restrict__ csr_src, int E) {
    int e = blockIdx.x * blockDim.x + threadIdx.x;
    if (e >= E) return;
    int pos = atomicAdd(cursor + dst[e], 1);
    csr_src[pos] = src[e];
}

// one wave per dst node; lane owns cols 2*lane, 2*lane+1 (head = lane>>4).
// 4-edge manual unroll: all 12 loads issued before dependent math (MLP).
__global__ __launch_bounds__(256) void agg_pull(const int* __restrict__ off,
                                                const int* __restrict__ csr_src,
                                                const float* __restrict__ el,
                                                const float* __restrict__ er,
                                                const unsigned int* __restrict__ ft16p,
                                                float* __restrict__ out, int n_dst) {
    int node = (blockIdx.x * blockDim.x + threadIdx.x) >> 6;
    int lane = threadIdx.x & 63;
    if (node >= n_dst) return;
    const int h = lane >> 4;
    const float er_h = er[(size_t)node * 4 + h];
    const int start = off[node], end = off[node + 1];
    float a0 = 0.f, a1 = 0.f, sw = 0.f;
    int k = start;
    const int end4 = start + ((end - start) & ~3);
    for (; k < end4; k += 4) {
        const int s0 = csr_src[k];
        const int s1 = csr_src[k + 1];
        const int s2 = csr_src[k + 2];
        const int s3 = csr_src[k + 3];
        float x0 = el[(size_t)s0 * 4 + h];
        float x1 = el[(size_t)s1 * 4 + h];
        float x2 = el[(size_t)s2 * 4 + h];
        float x3 = el[(size_t)s3 * 4 + h];
        const unsigned int p0 = ft16p[(size_t)s0 * 64 + lane];
        const unsigned int p1 = ft16p[(size_t)s1 * 64 + lane];
        const unsigned int p2 = ft16p[(size_t)s2 * 64 + lane];
        const unsigned int p3 = ft16p[(size_t)s3 * 64 + lane];
        x0 += er_h; x0 = x0 > 0.f ? x0 : 0.2f * x0;
        x1 += er_h; x1 = x1 > 0.f ? x1 : 0.2f * x1;
        x2 += er_h; x2 = x2 > 0.f ? x2 : 0.2f * x2;
        x3 += er_h; x3 = x3 > 0.f ? x3 : 0.2f * x3;
        const float w0 = __expf(x0);
        const float w1 = __expf(x1);
        const float w2 = __expf(x2);
        const float w3 = __expf(x3);
        sw += w0 + w1 + w2 + w3;
        a0 += bfhi2f(p0 << 16) * w0 + bfhi2f(p1 << 16) * w1
            + bfhi2f(p2 << 16) * w2 + bfhi2f(p3 << 16) * w3;
        a1 += bfhi2f(p0 & 0xffff0000u) * w0 + bfhi2f(p1 & 0xffff0000u) * w1
            + bfhi2f(p2 & 0xffff0000u) * w2 + bfhi2f(p3 & 0xffff0000u) * w3;
    }
    for (; k < end; ++k) {
        const int s = csr_src[k];
        float x = el[(size_t)s * 4 + h] + er_h;
        x = x > 0.f ? x : 0.2f * x;
        const float w = __expf(x);
        const unsigned int p = ft16p[(size_t)s * 64 + lane];
        a0 += bfhi2f(p << 16) * w;
        a1 += bfhi2f(p & 0xffff0000u) * w;
        sw += w;
    }
    float2 r;
    r.x = (end > start) ? a0 / sw : 0.f;
    r.y = (end > start) ? a1 / sw : 0.f;
    *(float2*)(out + (size_t)node * NHF + 2 * lane) = r;
}

extern "C" void kernel_launch(void* const* d_in, const int* in_sizes, int n_in,
                              void* d_out, int out_size, void* d_ws, size_t ws_size,
                              hipStream_t stream) {
    const float* h_src  = (const float*)d_in[0];
    const float* h_dst  = (const float*)d_in[1];
    const float* W      = (const float*)d_in[2];
    const float* attn_l = (const float*)d_in[3];
    const float* attn_r = (const float*)d_in[4];
    const int* src_idx  = (const int*)d_in[5];
    const int* dst_idx  = (const int*)d_in[6];

    const int n_src = in_sizes[0] / IN_FEATS;   // 50000
    const int n_dst = in_sizes[1] / IN_FEATS;   // 50000
    const int E     = in_sizes[5];              // 800000

    const int nblk = (n_dst + 255) / 256;       // 196 (<=256 required by scan_top)

    // workspace layout
    char* ws = (char*)d_ws;
    size_t o = 0;
    float* v       = (float*)(ws + o); o += 4096;
    float* el      = (float*)(ws + o); o += (size_t)n_src * 4 * sizeof(float);
    float* er      = (float*)(ws + o); o += (size_t)n_dst * 4 * sizeof(float);
    int*   off     = (int*)(ws + o);   o += ((size_t)n_dst + 16) * sizeof(int);
    int*   cursor  = (int*)(ws + o);   o += ((size_t)n_dst + 16) * sizeof(int);
    int*   partial = (int*)(ws + o);   o += 256 * sizeof(int);
    int*   base    = (int*)(ws + o);   o += 256 * sizeof(int);
    unsigned short* Wt = (unsigned short*)(ws + o); o += (size_t)NHF * IN_FEATS * sizeof(unsigned short);
    int*   csr_src = (int*)(ws + o);   o += (size_t)E * sizeof(int);
    unsigned short* ft16 = (unsigned short*)(ws + o); o += (size_t)n_src * NHF * sizeof(unsigned short);
    int*   deg     = csr_src;          // alias: deg dead before csr_src written

    float* out = (float*)d_out;

    (void)hipMemsetAsync(deg, 0, (size_t)n_dst * sizeof(int), stream);

    prep<<<129, 256, 0, stream>>>(W, attn_r, v, Wt);
    gemm_el<<<(n_src + 63) / 64, 256, 0, stream>>>(h_src, Wt, attn_l, ft16, el, n_src);
    compute_er<<<(n_dst + 3) / 4, 256, 0, stream>>>(h_dst, v, er, n_dst);
    hist_dst<<<(E + 255) / 256, 256, 0, stream>>>(dst_idx, deg, E);
    scan_partial<<<nblk, 256, 0, stream>>>(deg, partial, n_dst);
    scan_top<<<1, 256, 0, stream>>>(partial, base, off, nblk, n_dst);
    scan_final<<<nblk, 256, 0, stream>>>(deg, base, off, cursor, n_dst);
    scatter_edges<<<(E + 255) / 256, 256, 0, stream>>>(src_idx, dst_idx, cursor, csr_src, E);
    agg_pull<<<(n_dst + 3) / 4, 256, 0, stream>>>(off, csr_src, el, er, (const unsigned int*)ft16, out, n_dst);
}

// Round 7
// 305.977 us; speedup vs baseline: 2.0295x; 1.0399x over previous
//
#include <hip/hip_runtime.h>

#define IN_FEATS 256
#define OUT_FEATS 32
#define NUM_HEADS 4
#define NHF 128   // NUM_HEADS*OUT_FEATS

typedef __attribute__((ext_vector_type(8))) short short8;
typedef __attribute__((ext_vector_type(4))) float f32x4;

__device__ inline unsigned short f2bf(float f) {
    unsigned int u = __builtin_bit_cast(unsigned int, f);
    u = (u + 0x7fff + ((u >> 16) & 1)) >> 16;   // RNE
    return (unsigned short)u;
}
__device__ inline float bfhi2f(unsigned int packed_hi) {   // bits already in [31:16]
    return __builtin_bit_cast(float, packed_hi);
}

// prep: blocks 0..127 transpose W -> Wt bf16 [128][256]; block 128 computes
// v[k*4+h] = sum_f W[k*128 + h*32 + f] * attn_r[h*32 + f]
__global__ __launch_bounds__(256) void prep(const float* __restrict__ W,
                                            const float* __restrict__ attn_r,
                                            float* __restrict__ v,
                                            unsigned short* __restrict__ Wt) {
    if (blockIdx.x < 128) {
        int n = blockIdx.x;
        int k = threadIdx.x;
        Wt[n * 256 + k] = f2bf(W[(size_t)k * NHF + n]);
    } else {
        for (int p = threadIdx.x; p < IN_FEATS * NUM_HEADS; p += 256) {
            int k = p >> 2, h = p & 3;
            const float* wr = W + (size_t)k * NHF + h * OUT_FEATS;
            const float* ar = attn_r + h * OUT_FEATS;
            float s = 0.f;
            #pragma unroll
            for (int f = 0; f < OUT_FEATS; ++f) s += wr[f] * ar[f];
            v[p] = s;
        }
    }
}

// ft16 = bf16(A @ W), el fused. One wave per 16 rows, MFMA 16x16x32 bf16.
// Wt staged in LDS (XOR-swizzled 16B chunks); all A loads hoisted pre-loop.
__global__ __launch_bounds__(256) void gemm_el(const float* __restrict__ A,
                                               const unsigned short* __restrict__ Wt,
                                               const float* __restrict__ attn_l,
                                               unsigned short* __restrict__ ft16,
                                               float* __restrict__ el, int M) {
    __shared__ unsigned short WtL[128 * 256];   // 64 KB, chunk (c,n) at ((c+n)&31)

    const int wave = threadIdx.x >> 6;
    const int lane = threadIdx.x & 63;
    const int quad = lane >> 4;
    const int mc   = lane & 15;
    const int row_base = blockIdx.x * 64 + wave * 16;

    // stage Wt -> LDS, swizzled: chunk c (16B) of row n stored at chunk ((c+n)&31)
    for (int i = threadIdx.x; i < 4096; i += 256) {
        const int n = i >> 5, c = i & 31;
        const int cs = (c + n) & 31;
        *(uint4*)(WtL + n * 256 + cs * 8) = *(const uint4*)(Wt + n * 256 + c * 8);
    }

    // attn_l regs: al[t] = attn_l[(t>>1)*32 + (t&1)*16 + mc]
    float al[8];
    #pragma unroll
    for (int t = 0; t < 8; ++t) al[t] = attn_l[(t >> 1) * 32 + (t & 1) * 16 + mc];

    const int rowA = min(row_base + mc, M - 1);
    const float* arow = A + (size_t)rowA * IN_FEATS;

    // hoist ALL A loads (16 float4, one HBM round-trip)
    float4 a[8][2];
    #pragma unroll
    for (int kk = 0; kk < 8; ++kk) {
        a[kk][0] = *(const float4*)(arow + kk * 32 + quad * 8);
        a[kk][1] = *(const float4*)(arow + kk * 32 + quad * 8 + 4);
    }

    f32x4 acc[8];
    #pragma unroll
    for (int t = 0; t < 8; ++t) acc[t] = (f32x4){0.f, 0.f, 0.f, 0.f};

    __syncthreads();

    #pragma unroll
    for (int kk = 0; kk < 8; ++kk) {
        short8 af;
        af[0] = (short)f2bf(a[kk][0].x); af[1] = (short)f2bf(a[kk][0].y);
        af[2] = (short)f2bf(a[kk][0].z); af[3] = (short)f2bf(a[kk][0].w);
        af[4] = (short)f2bf(a[kk][1].x); af[5] = (short)f2bf(a[kk][1].y);
        af[6] = (short)f2bf(a[kk][1].z); af[7] = (short)f2bf(a[kk][1].w);
        #pragma unroll
        for (int t = 0; t < 8; ++t) {
            const int n = t * 16 + mc;
            const int c = ((kk << 2) + quad + n) & 31;
            const short8 bf = *(const short8*)(WtL + n * 256 + c * 8);
            acc[t] = __builtin_amdgcn_mfma_f32_16x16x32_bf16(af, bf, acc[t], 0, 0, 0);
        }
    }

    // el partials from fp32 accs: elp[v][h]
    float elp[4][4];
    #pragma unroll
    for (int v = 0; v < 4; ++v)
        #pragma unroll
        for (int h = 0; h < 4; ++h) elp[v][h] = 0.f;
    #pragma unroll
    for (int v = 0; v < 4; ++v)
        #pragma unroll
        for (int t = 0; t < 8; ++t) elp[v][t >> 1] += acc[t][v] * al[t];
    #pragma unroll
    for (int v = 0; v < 4; ++v)
        #pragma unroll
        for (int h = 0; h < 4; ++h) {
            #pragma unroll
            for (int d = 1; d < 16; d <<= 1)
                elp[v][h] += __shfl_xor(elp[v][h], d, 64);
        }

    #pragma unroll
    for (int v = 0; v < 4; ++v) {
        const int rg = row_base + quad * 4 + v;
        if (rg < M) {
            unsigned short* o = ft16 + (size_t)rg * NHF;
            #pragma unroll
            for (int t = 0; t < 8; ++t) o[t * 16 + mc] = f2bf(acc[t][v]);
            if (mc < 4) {
                float ev = (mc == 0) ? elp[v][0] : (mc == 1) ? elp[v][1]
                         : (mc == 2) ? elp[v][2] : elp[v][3];
                el[(size_t)rg * 4 + mc] = ev;
            }
        }
    }
}

// er[n*4+h] = sum_k h_dst[n*256+k] * v[k*4+h]   (one wave per row)
__global__ __launch_bounds__(256) void compute_er(const float* __restrict__ hdst,
                                                  const float* __restrict__ v,
                                                  float* __restrict__ er, int M) {
    int wid  = (blockIdx.x * blockDim.x + threadIdx.x) >> 6;
    int lane = threadIdx.x & 63;
    if (wid >= M) return;
    const float4 x = *(const float4*)(hdst + (size_t)wid * IN_FEATS + lane * 4);
    const float4* vp = (const float4*)(v + (size_t)lane * 16);
    float4 v0 = vp[0], v1 = vp[1], v2 = vp[2], v3 = vp[3];
    float a0 = x.x * v0.x + x.y * v1.x + x.z * v2.x + x.w * v3.x;
    float a1 = x.x * v0.y + x.y * v1.y + x.z * v2.y + x.w * v3.y;
    float a2 = x.x * v0.z + x.y * v1.z + x.z * v2.z + x.w * v3.z;
    float a3 = x.x * v0.w + x.y * v1.w + x.z * v2.w + x.w * v3.w;
    #pragma unroll
    for (int m = 32; m >= 1; m >>= 1) {
        a0 += __shfl_xor(a0, m, 64);
        a1 += __shfl_xor(a1, m, 64);
        a2 += __shfl_xor(a2, m, 64);
        a3 += __shfl_xor(a3, m, 64);
    }
    if (lane == 0) *(float4*)(er + (size_t)wid * 4) = make_float4(a0, a1, a2, a3);
}

// deg[dst[e]]++
__global__ void hist_dst(const int* __restrict__ dst, int* __restrict__ deg, int E) {
    int e = blockIdx.x * blockDim.x + threadIdx.x;
    if (e < E) atomicAdd(deg + dst[e], 1);
}

// ---- hierarchical exclusive scan ----
__global__ __launch_bounds__(256) void scan_partial(const int* __restrict__ deg,
                                                    int* __restrict__ partial, int n) {
    __shared__ int red[4];
    int i = blockIdx.x * 256 + threadIdx.x;
    int v = (i < n) ? deg[i] : 0;
    #pragma unroll
    for (int m = 32; m >= 1; m >>= 1) v += __shfl_xor(v, m, 64);
    int wave = threadIdx.x >> 6, lane = threadIdx.x & 63;
    if (lane == 0) red[wave] = v;
    __syncthreads();
    if (threadIdx.x == 0) partial[blockIdx.x] = red[0] + red[1] + red[2] + red[3];
}

__global__ __launch_bounds__(256) void scan_top(const int* __restrict__ partial,
                                                int* __restrict__ base,
                                                int* __restrict__ off, int nblk, int n) {
    __shared__ int s[256];
    int t = threadIdx.x;
    int v = (t < nblk) ? partial[t] : 0;
    s[t] = v;
    __syncthreads();
    #pragma unroll
    for (int d = 1; d < 256; d <<= 1) {
        int x = (t >= d) ? s[t - d] : 0;
        __syncthreads();
        s[t] += x;
        __syncthreads();
    }
    if (t < nblk) base[t] = s[t] - v;
    if (t == 255) off[n] = s[255];
}

__global__ __launch_bounds__(256) void scan_final(const int* __restrict__ deg,
                                                  const int* __restrict__ base,
                                                  int* __restrict__ off,
                                                  int* __restrict__ cursor, int n) {
    __shared__ int s[256];
    int i = blockIdx.x * 256 + threadIdx.x;
    int t = threadIdx.x;
    int v = (i < n) ? deg[i] : 0;
    s[t] = v;
    __syncthreads();
    #pragma unroll
    for (int d = 1; d < 256; d <<= 1) {
        int x = (t >= d) ? s[t - d] : 0;
        __syncthreads();
        s[t] += x;
        __syncthreads();
    }
    int ex = s[t] - v + base[blockIdx.x];
    if (i < n) { off[i] = ex; cursor[i] = ex; }
}

// csr_src[pos] = src[e] for pos = cursor[dst[e]]++  (non-temporal scatter)
__global__ void scatter_edges(const int* __restrict__ src, const int* __restrict__ dst,
                              int* __restrict__ cursor, int* __restrict__ csr_src, int E) {
    int e = blockIdx.x * blockDim.x + threadIdx.x;
    if (e >= E) return;
    int pos = atomicAdd(cursor + dst[e], 1);
    __builtin_nontemporal_store(src[e], csr_src + pos);
}

// one wave per dst node; lane owns cols 2*lane, 2*lane+1 (head = lane>>4).
// 4-edge manual unroll: all 12 loads issued before dependent math (MLP).
__global__ __launch_bounds__(256) void agg_pull(const int* __restrict__ off,
                                                const int* __restrict__ csr_src,
                                                const float* __restrict__ el,
                                                const float* __restrict__ er,
                                                const unsigned int* __restrict__ ft16p,
                                                float* __restrict__ out, int n_dst) {
    int node = (blockIdx.x * blockDim.x + threadIdx.x) >> 6;
    int lane = threadIdx.x & 63;
    if (node >= n_dst) return;
    const int h = lane >> 4;
    const float er_h = er[(size_t)node * 4 + h];
    const int start = off[node], end = off[node + 1];
    float a0 = 0.f, a1 = 0.f, sw = 0.f;
    int k = start;
    const int end4 = start + ((end - start) & ~3);
    for (; k < end4; k += 4) {
        const int s0 = csr_src[k];
        const int s1 = csr_src[k + 1];
        const int s2 = csr_src[k + 2];
        const int s3 = csr_src[k + 3];
        float x0 = el[(size_t)s0 * 4 + h];
        float x1 = el[(size_t)s1 * 4 + h];
        float x2 = el[(size_t)s2 * 4 + h];
        float x3 = el[(size_t)s3 * 4 + h];
        const unsigned int p0 = ft16p[(size_t)s0 * 64 + lane];
        const unsigned int p1 = ft16p[(size_t)s1 * 64 + lane];
        const unsigned int p2 = ft16p[(size_t)s2 * 64 + lane];
        const unsigned int p3 = ft16p[(size_t)s3 * 64 + lane];
        x0 += er_h; x0 = x0 > 0.f ? x0 : 0.2f * x0;
        x1 += er_h; x1 = x1 > 0.f ? x1 : 0.2f * x1;
        x2 += er_h; x2 = x2 > 0.f ? x2 : 0.2f * x2;
        x3 += er_h; x3 = x3 > 0.f ? x3 : 0.2f * x3;
        const float w0 = __expf(x0);
        const float w1 = __expf(x1);
        const float w2 = __expf(x2);
        const float w3 = __expf(x3);
        sw += w0 + w1 + w2 + w3;
        a0 += bfhi2f(p0 << 16) * w0 + bfhi2f(p1 << 16) * w1
            + bfhi2f(p2 << 16) * w2 + bfhi2f(p3 << 16) * w3;
        a1 += bfhi2f(p0 & 0xffff0000u) * w0 + bfhi2f(p1 & 0xffff0000u) * w1
            + bfhi2f(p2 & 0xffff0000u) * w2 + bfhi2f(p3 & 0xffff0000u) * w3;
    }
    for (; k < end; ++k) {
        const int s = csr_src[k];
        float x = el[(size_t)s * 4 + h] + er_h;
        x = x > 0.f ? x : 0.2f * x;
        const float w = __expf(x);
        const unsigned int p = ft16p[(size_t)s * 64 + lane];
        a0 += bfhi2f(p << 16) * w;
        a1 += bfhi2f(p & 0xffff0000u) * w;
        sw += w;
    }
    float2 r;
    r.x = (end > start) ? a0 / sw : 0.f;
    r.y = (end > start) ? a1 / sw : 0.f;
    *(float2*)(out + (size_t)node * NHF + 2 * lane) = r;
}

extern "C" void kernel_launch(void* const* d_in, const int* in_sizes, int n_in,
                              void* d_out, int out_size, void* d_ws, size_t ws_size,
                              hipStream_t stream) {
    const float* h_src  = (const float*)d_in[0];
    const float* h_dst  = (const float*)d_in[1];
    const float* W      = (const float*)d_in[2];
    const float* attn_l = (const float*)d_in[3];
    const float* attn_r = (const float*)d_in[4];
    const int* src_idx  = (const int*)d_in[5];
    const int* dst_idx  = (const int*)d_in[6];

    const int n_src = in_sizes[0] / IN_FEATS;   // 50000
    const int n_dst = in_sizes[1] / IN_FEATS;   // 50000
    const int E     = in_sizes[5];              // 800000

    const int nblk = (n_dst + 255) / 256;       // 196 (<=256 required by scan_top)

    // workspace layout
    char* ws = (char*)d_ws;
    size_t o = 0;
    float* v       = (float*)(ws + o); o += 4096;
    float* el      = (float*)(ws + o); o += (size_t)n_src * 4 * sizeof(float);
    float* er      = (float*)(ws + o); o += (size_t)n_dst * 4 * sizeof(float);
    int*   off     = (int*)(ws + o);   o += ((size_t)n_dst + 16) * sizeof(int);
    int*   cursor  = (int*)(ws + o);   o += ((size_t)n_dst + 16) * sizeof(int);
    int*   partial = (int*)(ws + o);   o += 256 * sizeof(int);
    int*   base    = (int*)(ws + o);   o += 256 * sizeof(int);
    unsigned short* Wt = (unsigned short*)(ws + o); o += (size_t)NHF * IN_FEATS * sizeof(unsigned short);
    int*   csr_src = (int*)(ws + o);   o += (size_t)E * sizeof(int);
    unsigned short* ft16 = (unsigned short*)(ws + o); o += (size_t)n_src * NHF * sizeof(unsigned short);
    int*   deg     = csr_src;          // alias: deg dead before csr_src written

    float* out = (float*)d_out;

    (void)hipMemsetAsync(deg, 0, (size_t)n_dst * sizeof(int), stream);

    prep<<<129, 256, 0, stream>>>(W, attn_r, v, Wt);
    gemm_el<<<(n_src + 63) / 64, 256, 0, stream>>>(h_src, Wt, attn_l, ft16, el, n_src);
    compute_er<<<(n_dst + 3) / 4, 256, 0, stream>>>(h_dst, v, er, n_dst);
    hist_dst<<<(E + 255) / 256, 256, 0, stream>>>(dst_idx, deg, E);
    scan_partial<<<nblk, 256, 0, stream>>>(deg, partial, n_dst);
    scan_top<<<1, 256, 0, stream>>>(partial, base, off, nblk, n_dst);
    scan_final<<<nblk, 256, 0, stream>>>(deg, base, off, cursor, n_dst);
    scatter_edges<<<(E + 255) / 256, 256, 0, stream>>>(src_idx, dst_idx, cursor, csr_src, E);
    agg_pull<<<(n_dst + 3) / 4, 256, 0, stream>>>(off, csr_src, el, er, (const unsigned int*)ft16, out, n_dst);
}

// Round 8
// 260.042 us; speedup vs baseline: 2.3880x; 1.1766x over previous
//
#include <hip/hip_runtime.h>

#define IN_FEATS 256
#define OUT_FEATS 32
#define NUM_HEADS 4
#define NHF 128   // NUM_HEADS*OUT_FEATS

typedef __attribute__((ext_vector_type(8))) short short8;
typedef __attribute__((ext_vector_type(4))) float f32x4;

__device__ inline unsigned short f2bf(float f) {
    unsigned int u = __builtin_bit_cast(unsigned int, f);
    u = (u + 0x7fff + ((u >> 16) & 1)) >> 16;   // RNE
    return (unsigned short)u;
}
__device__ inline float bfhi2f(unsigned int packed_hi) {   // bits already in [31:16]
    return __builtin_bit_cast(float, packed_hi);
}

// prep: blocks 0..127 transpose W -> Wt bf16 [128][256]; block 128 computes
// v[k*4+h] = sum_f W[k*128 + h*32 + f] * attn_r[h*32 + f]
__global__ __launch_bounds__(256) void prep(const float* __restrict__ W,
                                            const float* __restrict__ attn_r,
                                            float* __restrict__ v,
                                            unsigned short* __restrict__ Wt) {
    if (blockIdx.x < 128) {
        int n = blockIdx.x;
        int k = threadIdx.x;
        Wt[n * 256 + k] = f2bf(W[(size_t)k * NHF + n]);
    } else {
        for (int p = threadIdx.x; p < IN_FEATS * NUM_HEADS; p += 256) {
            int k = p >> 2, h = p & 3;
            const float* wr = W + (size_t)k * NHF + h * OUT_FEATS;
            const float* ar = attn_r + h * OUT_FEATS;
            float s = 0.f;
            #pragma unroll
            for (int f = 0; f < OUT_FEATS; ++f) s += wr[f] * ar[f];
            v[p] = s;
        }
    }
}

// ft16 = bf16(A @ W), el fused. One wave per 16 rows, MFMA 16x16x32 bf16.
// Wt staged in LDS (XOR-swizzled 16B chunks); all A loads hoisted pre-loop.
__global__ __launch_bounds__(256) void gemm_el(const float* __restrict__ A,
                                               const unsigned short* __restrict__ Wt,
                                               const float* __restrict__ attn_l,
                                               unsigned short* __restrict__ ft16,
                                               float* __restrict__ el, int M) {
    __shared__ unsigned short WtL[128 * 256];   // 64 KB, chunk (c,n) at ((c+n)&31)

    const int wave = threadIdx.x >> 6;
    const int lane = threadIdx.x & 63;
    const int quad = lane >> 4;
    const int mc   = lane & 15;
    const int row_base = blockIdx.x * 64 + wave * 16;

    for (int i = threadIdx.x; i < 4096; i += 256) {
        const int n = i >> 5, c = i & 31;
        const int cs = (c + n) & 31;
        *(uint4*)(WtL + n * 256 + cs * 8) = *(const uint4*)(Wt + n * 256 + c * 8);
    }

    float al[8];
    #pragma unroll
    for (int t = 0; t < 8; ++t) al[t] = attn_l[(t >> 1) * 32 + (t & 1) * 16 + mc];

    const int rowA = min(row_base + mc, M - 1);
    const float* arow = A + (size_t)rowA * IN_FEATS;

    float4 a[8][2];
    #pragma unroll
    for (int kk = 0; kk < 8; ++kk) {
        a[kk][0] = *(const float4*)(arow + kk * 32 + quad * 8);
        a[kk][1] = *(const float4*)(arow + kk * 32 + quad * 8 + 4);
    }

    f32x4 acc[8];
    #pragma unroll
    for (int t = 0; t < 8; ++t) acc[t] = (f32x4){0.f, 0.f, 0.f, 0.f};

    __syncthreads();

    #pragma unroll
    for (int kk = 0; kk < 8; ++kk) {
        short8 af;
        af[0] = (short)f2bf(a[kk][0].x); af[1] = (short)f2bf(a[kk][0].y);
        af[2] = (short)f2bf(a[kk][0].z); af[3] = (short)f2bf(a[kk][0].w);
        af[4] = (short)f2bf(a[kk][1].x); af[5] = (short)f2bf(a[kk][1].y);
        af[6] = (short)f2bf(a[kk][1].z); af[7] = (short)f2bf(a[kk][1].w);
        #pragma unroll
        for (int t = 0; t < 8; ++t) {
            const int n = t * 16 + mc;
            const int c = ((kk << 2) + quad + n) & 31;
            const short8 bf = *(const short8*)(WtL + n * 256 + c * 8);
            acc[t] = __builtin_amdgcn_mfma_f32_16x16x32_bf16(af, bf, acc[t], 0, 0, 0);
        }
    }

    float elp[4][4];
    #pragma unroll
    for (int v = 0; v < 4; ++v)
        #pragma unroll
        for (int h = 0; h < 4; ++h) elp[v][h] = 0.f;
    #pragma unroll
    for (int v = 0; v < 4; ++v)
        #pragma unroll
        for (int t = 0; t < 8; ++t) elp[v][t >> 1] += acc[t][v] * al[t];
    #pragma unroll
    for (int v = 0; v < 4; ++v)
        #pragma unroll
        for (int h = 0; h < 4; ++h) {
            #pragma unroll
            for (int d = 1; d < 16; d <<= 1)
                elp[v][h] += __shfl_xor(elp[v][h], d, 64);
        }

    #pragma unroll
    for (int v = 0; v < 4; ++v) {
        const int rg = row_base + quad * 4 + v;
        if (rg < M) {
            unsigned short* o = ft16 + (size_t)rg * NHF;
            #pragma unroll
            for (int t = 0; t < 8; ++t) o[t * 16 + mc] = f2bf(acc[t][v]);
            if (mc < 4) {
                float ev = (mc == 0) ? elp[v][0] : (mc == 1) ? elp[v][1]
                         : (mc == 2) ? elp[v][2] : elp[v][3];
                el[(size_t)rg * 4 + mc] = ev;
            }
        }
    }
}

// er[n*4+h] = sum_k h_dst[n*256+k] * v[k*4+h]   (one wave per row)
__global__ __launch_bounds__(256) void compute_er(const float* __restrict__ hdst,
                                                  const float* __restrict__ v,
                                                  float* __restrict__ er, int M) {
    int wid  = (blockIdx.x * blockDim.x + threadIdx.x) >> 6;
    int lane = threadIdx.x & 63;
    if (wid >= M) return;
    const float4 x = *(const float4*)(hdst + (size_t)wid * IN_FEATS + lane * 4);
    const float4* vp = (const float4*)(v + (size_t)lane * 16);
    float4 v0 = vp[0], v1 = vp[1], v2 = vp[2], v3 = vp[3];
    float a0 = x.x * v0.x + x.y * v1.x + x.z * v2.x + x.w * v3.x;
    float a1 = x.x * v0.y + x.y * v1.y + x.z * v2.y + x.w * v3.y;
    float a2 = x.x * v0.z + x.y * v1.z + x.z * v2.z + x.w * v3.z;
    float a3 = x.x * v0.w + x.y * v1.w + x.z * v2.w + x.w * v3.w;
    #pragma unroll
    for (int m = 32; m >= 1; m >>= 1) {
        a0 += __shfl_xor(a0, m, 64);
        a1 += __shfl_xor(a1, m, 64);
        a2 += __shfl_xor(a2, m, 64);
        a3 += __shfl_xor(a3, m, 64);
    }
    if (lane == 0) *(float4*)(er + (size_t)wid * 4) = make_float4(a0, a1, a2, a3);
}

// ---- two-level counting sort by dst (bucket = dst>>8) ----

// coarse histogram, LDS-reduced
__global__ __launch_bounds__(256) void bucket_hist(const int* __restrict__ dst,
                                                   int* __restrict__ bcnt, int E) {
    __shared__ int h[256];
    h[threadIdx.x] = 0;
    __syncthreads();
    for (int e = blockIdx.x * 256 + threadIdx.x; e < E; e += gridDim.x * 256)
        atomicAdd(&h[dst[e] >> 8], 1);
    __syncthreads();
    int c = h[threadIdx.x];
    if (c) atomicAdd(&bcnt[threadIdx.x], c);
}

// 1 block: exclusive scan of 256 bucket counts -> bbase[257], bcursor; off[n]=E
__global__ __launch_bounds__(256) void bucket_scan(const int* __restrict__ bcnt,
                                                   int* __restrict__ bbase,
                                                   int* __restrict__ bcursor,
                                                   int* __restrict__ off, int n_dst, int E) {
    __shared__ int s[256];
    int t = threadIdx.x;
    int v = bcnt[t];
    s[t] = v;
    __syncthreads();
    #pragma unroll
    for (int d = 1; d < 256; d <<= 1) {
        int x = (t >= d) ? s[t - d] : 0;
        __syncthreads();
        s[t] += x;
        __syncthreads();
    }
    int ex = s[t] - v;
    bbase[t] = ex;
    bcursor[t] = ex;
    if (t == 255) bbase[256] = s[255];
    if (t == 0) off[n_dst] = E;
}

// per-chunk (4096 edges) binning: count, reserve contiguous runs, write pairs
__global__ __launch_bounds__(256) void bin_pairs(const int* __restrict__ src,
                                                 const int* __restrict__ dst,
                                                 int* __restrict__ bcursor,
                                                 int2* __restrict__ pairs, int E) {
    __shared__ int cnt[256];
    __shared__ int basel[256];
    const int e0 = blockIdx.x * 4096;
    const int e1 = min(e0 + 4096, E);
    const int t = threadIdx.x;
    cnt[t] = 0;
    __syncthreads();
    for (int e = e0 + t; e < e1; e += 256)
        atomicAdd(&cnt[dst[e] >> 8], 1);
    __syncthreads();
    int c = cnt[t];
    basel[t] = c ? atomicAdd(&bcursor[t], c) : 0;
    __syncthreads();
    cnt[t] = 0;
    __syncthreads();
    for (int e = e0 + t; e < e1; e += 256) {
        int d = dst[e];
        int b = d >> 8;
        int o = atomicAdd(&cnt[b], 1);
        pairs[basel[b] + o] = make_int2(src[e], d);
    }
}

// one block per bucket: exact CSR within the bucket's contiguous region
__global__ __launch_bounds__(256) void fine_csr(const int2* __restrict__ pairs,
                                                const int* __restrict__ bbase,
                                                int* __restrict__ off,
                                                int* __restrict__ csr_src, int n_dst) {
    __shared__ int cnt[256];
    __shared__ int cur[256];
    const int b = blockIdx.x;
    const int p0 = bbase[b], p1 = bbase[b + 1];
    const int t = threadIdx.x;
    cnt[t] = 0;
    __syncthreads();
    for (int p = p0 + t; p < p1; p += 256)
        atomicAdd(&cnt[pairs[p].y & 255], 1);
    __syncthreads();
    int v = cnt[t];
    cur[t] = v;
    __syncthreads();
    #pragma unroll
    for (int d = 1; d < 256; d <<= 1) {
        int x = (t >= d) ? cur[t - d] : 0;
        __syncthreads();
        cur[t] += x;
        __syncthreads();
    }
    int ex = cur[t] - v;
    int node = b * 256 + t;
    if (node < n_dst) off[node] = p0 + ex;
    __syncthreads();
    cur[t] = ex;
    __syncthreads();
    for (int p = p0 + t; p < p1; p += 256) {
        int2 pr = pairs[p];
        int o = atomicAdd(&cur[pr.y & 255], 1);
        csr_src[p0 + o] = pr.x;
    }
}

// one wave per dst node; lane owns cols 2*lane, 2*lane+1 (head = lane>>4).
// 4-edge manual unroll: all 12 loads issued before dependent math (MLP).
__global__ __launch_bounds__(256) void agg_pull(const int* __restrict__ off,
                                                const int* __restrict__ csr_src,
                                                const float* __restrict__ el,
                                                const float* __restrict__ er,
                                                const unsigned int* __restrict__ ft16p,
                                                float* __restrict__ out, int n_dst) {
    int node = (blockIdx.x * blockDim.x + threadIdx.x) >> 6;
    int lane = threadIdx.x & 63;
    if (node >= n_dst) return;
    const int h = lane >> 4;
    const float er_h = er[(size_t)node * 4 + h];
    const int start = off[node], end = off[node + 1];
    float a0 = 0.f, a1 = 0.f, sw = 0.f;
    int k = start;
    const int end4 = start + ((end - start) & ~3);
    for (; k < end4; k += 4) {
        const int s0 = csr_src[k];
        const int s1 = csr_src[k + 1];
        const int s2 = csr_src[k + 2];
        const int s3 = csr_src[k + 3];
        float x0 = el[(size_t)s0 * 4 + h];
        float x1 = el[(size_t)s1 * 4 + h];
        float x2 = el[(size_t)s2 * 4 + h];
        float x3 = el[(size_t)s3 * 4 + h];
        const unsigned int p0 = ft16p[(size_t)s0 * 64 + lane];
        const unsigned int p1 = ft16p[(size_t)s1 * 64 + lane];
        const unsigned int p2 = ft16p[(size_t)s2 * 64 + lane];
        const unsigned int p3 = ft16p[(size_t)s3 * 64 + lane];
        x0 += er_h; x0 = x0 > 0.f ? x0 : 0.2f * x0;
        x1 += er_h; x1 = x1 > 0.f ? x1 : 0.2f * x1;
        x2 += er_h; x2 = x2 > 0.f ? x2 : 0.2f * x2;
        x3 += er_h; x3 = x3 > 0.f ? x3 : 0.2f * x3;
        const float w0 = __expf(x0);
        const float w1 = __expf(x1);
        const float w2 = __expf(x2);
        const float w3 = __expf(x3);
        sw += w0 + w1 + w2 + w3;
        a0 += bfhi2f(p0 << 16) * w0 + bfhi2f(p1 << 16) * w1
            + bfhi2f(p2 << 16) * w2 + bfhi2f(p3 << 16) * w3;
        a1 += bfhi2f(p0 & 0xffff0000u) * w0 + bfhi2f(p1 & 0xffff0000u) * w1
            + bfhi2f(p2 & 0xffff0000u) * w2 + bfhi2f(p3 & 0xffff0000u) * w3;
    }
    for (; k < end; ++k) {
        const int s = csr_src[k];
        float x = el[(size_t)s * 4 + h] + er_h;
        x = x > 0.f ? x : 0.2f * x;
        const float w = __expf(x);
        const unsigned int p = ft16p[(size_t)s * 64 + lane];
        a0 += bfhi2f(p << 16) * w;
        a1 += bfhi2f(p & 0xffff0000u) * w;
        sw += w;
    }
    float2 r;
    r.x = (end > start) ? a0 / sw : 0.f;
    r.y = (end > start) ? a1 / sw : 0.f;
    *(float2*)(out + (size_t)node * NHF + 2 * lane) = r;
}

extern "C" void kernel_launch(void* const* d_in, const int* in_sizes, int n_in,
                              void* d_out, int out_size, void* d_ws, size_t ws_size,
                              hipStream_t stream) {
    const float* h_src  = (const float*)d_in[0];
    const float* h_dst  = (const float*)d_in[1];
    const float* W      = (const float*)d_in[2];
    const float* attn_l = (const float*)d_in[3];
    const float* attn_r = (const float*)d_in[4];
    const int* src_idx  = (const int*)d_in[5];
    const int* dst_idx  = (const int*)d_in[6];

    const int n_src = in_sizes[0] / IN_FEATS;   // 50000
    const int n_dst = in_sizes[1] / IN_FEATS;   // 50000
    const int E     = in_sizes[5];              // 800000

    const int nbuck = (n_dst + 255) >> 8;       // 196 (<=256)

    // workspace layout
    char* ws = (char*)d_ws;
    size_t o = 0;
    float* v       = (float*)(ws + o); o += 4096;
    float* el      = (float*)(ws + o); o += (size_t)n_src * 4 * sizeof(float);
    float* er      = (float*)(ws + o); o += (size_t)n_dst * 4 * sizeof(float);
    int*   off     = (int*)(ws + o);   o += ((size_t)n_dst + 16) * sizeof(int);
    int*   bcnt    = (int*)(ws + o);   o += 256 * sizeof(int);
    int*   bbase   = (int*)(ws + o);   o += 260 * sizeof(int);
    int*   bcursor = (int*)(ws + o);   o += 256 * sizeof(int);
    unsigned short* Wt = (unsigned short*)(ws + o); o += (size_t)NHF * IN_FEATS * sizeof(unsigned short);
    int*   csr_src = (int*)(ws + o);   o += (size_t)E * sizeof(int);
    int2*  pairs   = (int2*)(ws + o);  o += (size_t)E * sizeof(int2);
    unsigned short* ft16 = (unsigned short*)(ws + o); o += (size_t)n_src * NHF * sizeof(unsigned short);

    float* out = (float*)d_out;

    (void)hipMemsetAsync(bcnt, 0, 256 * sizeof(int), stream);

    prep<<<129, 256, 0, stream>>>(W, attn_r, v, Wt);
    gemm_el<<<(n_src + 63) / 64, 256, 0, stream>>>(h_src, Wt, attn_l, ft16, el, n_src);
    compute_er<<<(n_dst + 3) / 4, 256, 0, stream>>>(h_dst, v, er, n_dst);
    bucket_hist<<<512, 256, 0, stream>>>(dst_idx, bcnt, E);
    bucket_scan<<<1, 256, 0, stream>>>(bcnt, bbase, bcursor, off, n_dst, E);
    bin_pairs<<<(E + 4095) / 4096, 256, 0, stream>>>(src_idx, dst_idx, bcursor, pairs, E);
    fine_csr<<<nbuck, 256, 0, stream>>>(pairs, bbase, off, csr_src, n_dst);
    agg_pull<<<(n_dst + 3) / 4, 256, 0, stream>>>(off, csr_src, el, er, (const unsigned int*)ft16, out, n_dst);
}